// Round 1
// baseline (430.169 us; speedup 1.0000x reference)
//
#include <hip/hip_runtime.h>

// TensorTrain: BS=16384, N_CH=8, H=256, RANK=16, N_AGGR=4, T=64, R=(16+1)*16=272
// Only r < 256 of ris is ever used (U_rank rows 0..15, b_rank = row 15).
// Fused single-pass: per wave = one aggregator, 64 samples; bf16 MFMA GEMM
// (16x16x32) per channel, scan fused via shuffle-broadcast of carry, f32 epilogue.

#define N_CH   8
#define H_DIM  256
#define RANK_  16
#define N_AGGR 4
#define T_DIM  64
#define R_FULL 272
#define R_USE  256

typedef __bf16 bf16x8 __attribute__((ext_vector_type(8)));
typedef float  f32x4  __attribute__((ext_vector_type(4)));

union BF8 {
  bf16x8 v;
  unsigned short s[8];
  uint4 q;
};

static __device__ __forceinline__ unsigned short f2bf(float x) {
  union { float f; unsigned int u; } t; t.f = x;
  unsigned int u = t.u;
  return (unsigned short)((u + 0x7FFFu + ((u >> 16) & 1u)) >> 16); // RNE
}

// Convert U[c][a][h][r] (f32, r<256 only) -> Ubf[ca][r][h] (bf16), i.e. B in
// [n][k] layout so a B-fragment (n = lane&15, k = (lane>>4)*8+j) is one
// contiguous 16B load. Each thread packs 2 h-adjacent elements into one uint.
__global__ void prep_U_kernel(const float* __restrict__ U, unsigned int* __restrict__ Ubf) {
  unsigned int idx = blockIdx.x * 256u + threadIdx.x;   // 8*4*256*128 = 1,048,576
  unsigned int r  = idx & 255u;
  unsigned int hp = (idx >> 8) & 127u;
  unsigned int ca = idx >> 15;
  const float* src = U + (size_t)(ca * 256u + 2u * hp) * 272u + r;  // coalesced in r
  unsigned int lo = f2bf(src[0]);
  unsigned int hi = f2bf(src[272]);
  Ubf[(ca * 256u + r) * 128u + hp] = lo | (hi << 16);
}

__global__ __launch_bounds__(256, 1)
void tt_main(const float* __restrict__ nh,            // (BS, 8, 256)
             const float* __restrict__ ty,            // (BS, 64)
             const unsigned short* __restrict__ Ubf,  // (32, 256, 256) bf16 [ca][r][h]
             const float* __restrict__ bB,            // (8, 4, 1, 272)
             const float* __restrict__ Ut,            // (4, 64, 16)
             const float* __restrict__ bt,            // (4, 1, 16)
             const float* __restrict__ Uo,            // (4, 16, 256)
             const float* __restrict__ bo,            // (4, 1, 256)
             float* __restrict__ out)                 // (BS, 1024)
{
  const int lane = threadIdx.x & 63;
  const int a    = threadIdx.x >> 6;     // wave id = aggregator
  const int b0   = blockIdx.x * 64;      // 64 samples per workgroup
  const int lr   = lane & 15;            // m (A-frag / C col) or n (B-frag)
  const int lg   = lane >> 4;            // k-group (quad)

  // ---- carry init: rank_ris0 = ty @ U_type[a] + b_type[a]  (K=64, 2 MFMAs/mt)
  f32x4 carry[4];
  {
    float btv = bt[a * 16 + lr];
    BF8 utf[2];
#pragma unroll
    for (int ks = 0; ks < 2; ++ks)
#pragma unroll
      for (int j = 0; j < 8; ++j)
        utf[ks].s[j] = f2bf(Ut[a * 1024 + (ks * 32 + lg * 8 + j) * 16 + lr]);
#pragma unroll
    for (int mt = 0; mt < 4; ++mt) {
      f32x4 acc = { btv, btv, btv, btv };
#pragma unroll
      for (int ks = 0; ks < 2; ++ks) {
        BF8 af;
        const float* src = ty + (size_t)(b0 + mt * 16 + lr) * 64 + ks * 32 + lg * 8;
#pragma unroll
        for (int j = 0; j < 8; ++j) af.s[j] = f2bf(src[j]);
        acc = __builtin_amdgcn_mfma_f32_16x16x32_bf16(af.v, utf[ks].v, acc, 0, 0, 0);
      }
      carry[mt] = acc;
    }
  }

  // ---- channel scan: 8 sequential bf16 GEMMs (64 x 256 x 256) fused with scan
#pragma unroll 1
  for (int c = 0; c < N_CH; ++c) {
    // A fragments for this channel: 64 rows x K=256, kept in registers (128 VGPR)
    BF8 Af[4][8];
#pragma unroll
    for (int mt = 0; mt < 4; ++mt)
#pragma unroll
      for (int ks = 0; ks < 8; ++ks) {
        const float* src = nh + (size_t)(b0 + mt * 16 + lr) * (N_CH * H_DIM)
                              + c * H_DIM + ks * 32 + lg * 8;
        float4 x0 = *(const float4*)(src);
        float4 x1 = *(const float4*)(src + 4);
        BF8 f;
        f.s[0] = f2bf(x0.x); f.s[1] = f2bf(x0.y); f.s[2] = f2bf(x0.z); f.s[3] = f2bf(x0.w);
        f.s[4] = f2bf(x1.x); f.s[5] = f2bf(x1.y); f.s[6] = f2bf(x1.z); f.s[7] = f2bf(x1.w);
        Af[mt][ks] = f;
      }

    const float* bBc = bB + (c * 4 + a) * R_FULL;
    const unsigned short* Ub = Ubf + (size_t)(c * 4 + a) * 65536;

    f32x4 partial[4];
#pragma unroll
    for (int mt = 0; mt < 4; ++mt) partial[mt] = { 0.f, 0.f, 0.f, 0.f };

    BF8 Bf0[8], Bf1[8];
#pragma unroll
    for (int ks = 0; ks < 8; ++ks)
      Bf0[ks].q = *(const uint4*)(Ub + (size_t)lr * 256 + ks * 32 + lg * 8);

#pragma unroll 1
    for (int tp = 0; tp < 8; ++tp) {
      const int t0 = 2 * tp, t1 = 2 * tp + 1;
      // prefetch t1 B-frags
#pragma unroll
      for (int ks = 0; ks < 8; ++ks)
        Bf1[ks].q = *(const uint4*)(Ub + (size_t)(t1 * 16 + lr) * 256 + ks * 32 + lg * 8);
      // ---- tile t0
      {
        float bias = bBc[t0 * 16 + lr];
        f32x4 acc[4];
#pragma unroll
        for (int mt = 0; mt < 4; ++mt) acc[mt] = { bias, bias, bias, bias };
#pragma unroll
        for (int ks = 0; ks < 8; ++ks)
#pragma unroll
          for (int mt = 0; mt < 4; ++mt)
            acc[mt] = __builtin_amdgcn_mfma_f32_16x16x32_bf16(Af[mt][ks].v, Bf0[ks].v, acc[mt], 0, 0, 0);
        const int srcl = (lane & 48) | t0;
#pragma unroll
        for (int mt = 0; mt < 4; ++mt)
#pragma unroll
          for (int i = 0; i < 4; ++i) {
            float cv = __shfl(carry[mt][i], srcl, 64);
            partial[mt][i] += cv * acc[mt][i];
          }
      }
      // prefetch t0+2 B-frags
      if (tp < 7) {
#pragma unroll
        for (int ks = 0; ks < 8; ++ks)
          Bf0[ks].q = *(const uint4*)(Ub + (size_t)((t0 + 2) * 16 + lr) * 256 + ks * 32 + lg * 8);
      }
      // ---- tile t1 (t=15 also contributes the b_rank bias row: +1.0 weight)
      {
        float bias = bBc[t1 * 16 + lr];
        float extra = (tp == 7) ? 1.0f : 0.0f;
        f32x4 acc[4];
#pragma unroll
        for (int mt = 0; mt < 4; ++mt) acc[mt] = { bias, bias, bias, bias };
#pragma unroll
        for (int ks = 0; ks < 8; ++ks)
#pragma unroll
          for (int mt = 0; mt < 4; ++mt)
            acc[mt] = __builtin_amdgcn_mfma_f32_16x16x32_bf16(Af[mt][ks].v, Bf1[ks].v, acc[mt], 0, 0, 0);
        const int srcl = (lane & 48) | t1;
#pragma unroll
        for (int mt = 0; mt < 4; ++mt)
#pragma unroll
          for (int i = 0; i < 4; ++i) {
            float cv = __shfl(carry[mt][i], srcl, 64) + extra;
            partial[mt][i] += cv * acc[mt][i];
          }
      }
    }
#pragma unroll
    for (int mt = 0; mt < 4; ++mt) carry[mt] = partial[mt];
  }

  // ---- epilogue: out[b][a*256+h] = carry[b][a][:] @ Uo[a][:][h] + bo[a][h]  (f32)
  float uo[4][16], bov[4];
#pragma unroll
  for (int chk = 0; chk < 4; ++chk) {
    bov[chk] = bo[a * 256 + chk * 64 + lane];
#pragma unroll
    for (int r = 0; r < 16; ++r)
      uo[chk][r] = Uo[(size_t)a * 4096 + r * 256 + chk * 64 + lane];
  }
#pragma unroll
  for (int mt = 0; mt < 4; ++mt)
#pragma unroll
    for (int g = 0; g < 4; ++g)
#pragma unroll
      for (int i = 0; i < 4; ++i) {
        const int m = mt * 16 + g * 4 + i;
        float cv[16];
#pragma unroll
        for (int r = 0; r < 16; ++r) cv[r] = __shfl(carry[mt][i], (g << 4) | r, 64);
#pragma unroll
        for (int chk = 0; chk < 4; ++chk) {
          float v = bov[chk];
#pragma unroll
          for (int r = 0; r < 16; ++r) v += cv[r] * uo[chk][r];
          out[(size_t)(b0 + m) * 1024 + a * 256 + chk * 64 + lane] = v;
        }
      }
}

extern "C" void kernel_launch(void* const* d_in, const int* in_sizes, int n_in,
                              void* d_out, int out_size, void* d_ws, size_t ws_size,
                              hipStream_t stream) {
  const float* nh = (const float*)d_in[0];   // neighbour_h (16384, 8, 256)
  const float* ty = (const float*)d_in[1];   // type_embs   (16384, 64)
  const float* U  = (const float*)d_in[2];   // U           (8, 4, 256, 272)
  const float* bB = (const float*)d_in[3];   // b           (8, 4, 1, 272)
  const float* Ut = (const float*)d_in[4];   // U_type      (4, 64, 16)
  const float* bt = (const float*)d_in[5];   // b_type      (4, 1, 16)
  const float* Uo = (const float*)d_in[6];   // U_output    (4, 16, 256)
  const float* bo = (const float*)d_in[7];   // b_output    (4, 1, 256)
  float* out = (float*)d_out;

  unsigned int* Ubf32 = (unsigned int*)d_ws; // 4 MB bf16 repack of U (r<256)

  prep_U_kernel<<<4096, 256, 0, stream>>>(U, Ubf32);
  tt_main<<<256, 256, 0, stream>>>(nh, ty, (const unsigned short*)d_ws,
                                   bB, Ut, bt, Uo, bo, out);
}

// Round 2
// 372.263 us; speedup vs baseline: 1.1556x; 1.1556x over previous
//
#include <hip/hip_runtime.h>

// TensorTrain: BS=16384, N_CH=8, H=256, RANK=16, N_AGGR=4, T=64, R=(16+1)*16=272
// Only r < 256 of ris is used (U_rank rows 0..15, b_rank = row 15 of tile 15).
//
// Round-2 design: block = 1024 thr = 16 waves = 4 aggr x 4 sample-groups
// (64 samples/block), grid = 256 -> 4 waves/SIMD occupancy.
// B (U, bf16, prepped in MFMA-fragment order) streamed tile-by-tile into
// double-buffered LDS via global_load_lds (16B/lane); A staged per channel in
// LDS fragment order (one f32->bf16 conversion per element per block).
// Scan fused via shuffle-broadcast of carry; f32 VALU epilogue.

#define N_CH   8
#define H_DIM  256
#define R_FULL 272

typedef __bf16 bf16x8 __attribute__((ext_vector_type(8)));
typedef float  f32x4  __attribute__((ext_vector_type(4)));

union BF8 {
  bf16x8 v;
  unsigned short s[8];
  uint4 q;
};

typedef __attribute__((address_space(3))) unsigned int       lds_u32;
typedef __attribute__((address_space(1))) const unsigned int glb_u32;

static __device__ __forceinline__ unsigned short f2bf(float x) {
  union { float f; unsigned int u; } t; t.f = x;
  unsigned int u = t.u;
  return (unsigned short)((u + 0x7FFFu + ((u >> 16) & 1u)) >> 16); // RNE
}
static __device__ __forceinline__ unsigned int pk2(float a, float b) {
  return (unsigned int)f2bf(a) | ((unsigned int)f2bf(b) << 16);
}
static __device__ __forceinline__ void ll16(const void* g, void* l) {
  __builtin_amdgcn_global_load_lds((glb_u32*)g, (lds_u32*)l, 16, 0, 0);
}

// ---- prep: U[c][a][h][r<256] f32 -> bf16 in MFMA B-fragment order:
// Ubf[ca][t][ks][lane][j]  (j=0..7 bf16, 16B per lane-frag), where
//   r = t*16 + (lane&15), h = ks*32 + (lane>>4)*8 + j.
// Output uint index == thread idx by construction: idx = ca<<15|t<<11|ks<<8|lane<<2|jp
__global__ void prep_U_kernel(const float* __restrict__ U, unsigned int* __restrict__ Ubf) {
  unsigned int idx  = blockIdx.x * 256u + threadIdx.x;   // 1,048,576 total
  unsigned int jp   = idx & 3u;
  unsigned int lane = (idx >> 2) & 63u;
  unsigned int ks   = (idx >> 8) & 7u;
  unsigned int t    = (idx >> 11) & 15u;
  unsigned int ca   = idx >> 15;
  unsigned int h = ks * 32u + (lane >> 4) * 8u + jp * 2u;
  unsigned int r = t * 16u + (lane & 15u);
  const float* src = U + ((size_t)ca * 256u + h) * R_FULL + r;
  Ubf[idx] = pk2(src[0], src[R_FULL]);   // h, h+1
}

// LDS layout (dynamic, 96 KB):
//   A frags:  [sg][ks][lane] 16B  -> 4*8*64*16 = 32 KB      at offset 0
//   B buf0:   [aggr][ks][lane]16B -> 4*8*64*16 = 32 KB      at offset 32K
//   B buf1:   same                                          at offset 64K
#define SM_A  0
#define SM_B0 32768
#define SM_B1 65536

__global__ __launch_bounds__(1024)
void tt_main(const float* __restrict__ nh,            // (BS, 8, 256)
             const float* __restrict__ ty,            // (BS, 64)
             const char*  __restrict__ Ubf,           // frag-ordered bf16 U (4 MB)
             const float* __restrict__ bB,            // (8, 4, 1, 272)
             const float* __restrict__ Ut,            // (4, 64, 16)
             const float* __restrict__ bt,            // (4, 1, 16)
             const float* __restrict__ Uo,            // (4, 16, 256)
             const float* __restrict__ bo,            // (4, 1, 256)
             float* __restrict__ out)                 // (BS, 1024)
{
  extern __shared__ char smem[];
  const int tid  = threadIdx.x;
  const int lane = tid & 63;
  const int w    = tid >> 6;        // 0..15
  const int a    = w & 3;           // aggregator
  const int sg   = w >> 2;          // sample group (16 samples)
  const int b0   = blockIdx.x * 64; // block sample base
  const int row0 = b0 + sg * 16;    // wave sample base
  const int lr   = lane & 15;
  const int lg   = lane >> 4;

  // ---- carry init: rank_ris0 = ty @ U_type[a] + b_type[a]  (K=64 -> 2 MFMAs)
  f32x4 carry;
  {
    float btv = bt[a * 16 + lr];
    f32x4 acc = { btv, btv, btv, btv };
#pragma unroll
    for (int ks = 0; ks < 2; ++ks) {
      BF8 utf, af;
#pragma unroll
      for (int j = 0; j < 8; ++j) {
        utf.s[j] = f2bf(Ut[a * 1024 + (ks * 32 + lg * 8 + j) * 16 + lr]);
        af.s[j]  = f2bf(ty[(size_t)(row0 + lr) * 64 + ks * 32 + lg * 8 + j]);
      }
      acc = __builtin_amdgcn_mfma_f32_16x16x32_bf16(af.v, utf.v, acc, 0, 0, 0);
    }
    carry = acc;
  }

  // B-tile async loader: wave w copies chunks 2w, 2w+1 (chunk = (aggr,ks) = 1KB)
  auto issueB = [&](int c, int t, int bufoff) {
#pragma unroll
    for (int q = 0; q < 2; ++q) {
      const int ch = w * 2 + q;                       // 0..31
      const char* g = Ubf + (((((size_t)c * 4 + (ch >> 3)) * 16 + t) * 8 + (ch & 7)) << 10)
                          + lane * 16;
      ll16(g, smem + bufoff + ch * 1024);
    }
  };

  // ---- channel scan
#pragma unroll 1
  for (int c = 0; c < N_CH; ++c) {
    // stage A (this block's 64 samples, channel c) into LDS in fragment order
    {
      const int sg_s = tid >> 8;
      const int ksh  = (tid >> 6) & 3;
      const int ln   = tid & 63;
      const int row  = sg_s * 16 + (ln & 15);
#pragma unroll
      for (int p = 0; p < 2; ++p) {
        const int ks = ksh * 2 + p;
        const int k0 = ks * 32 + (ln >> 4) * 8;
        const float* s = nh + ((size_t)(b0 + row) * N_CH + c) * H_DIM + k0;
        float4 x0 = *(const float4*)s;
        float4 x1 = *(const float4*)(s + 4);
        uint4 qv;
        qv.x = pk2(x0.x, x0.y); qv.y = pk2(x0.z, x0.w);
        qv.z = pk2(x1.x, x1.y); qv.w = pk2(x1.z, x1.w);
        *(uint4*)(smem + SM_A + ((sg_s * 8 + ks) * 64 + ln) * 16) = qv;
      }
    }
    issueB(c, 0, SM_B0);
    __syncthreads();   // A visible; B tile 0 complete (per-wave vmcnt drain)

    // A fragments for this wave: 16 rows x K=256 (32 VGPR), reused by 16 tiles
    BF8 Af[8];
#pragma unroll
    for (int ks = 0; ks < 8; ++ks)
      Af[ks].q = *(const uint4*)(smem + SM_A + ((sg * 8 + ks) * 64 + lane) * 16);

    // per-channel bias values for this lane's r-column across the 16 tiles
    const float* bBp = bB + (c * 4 + a) * R_FULL;
    float bb[16];
#pragma unroll
    for (int t = 0; t < 16; ++t) bb[t] = bBp[t * 16 + lr];

    f32x4 partial = { 0.f, 0.f, 0.f, 0.f };

#pragma unroll 1
    for (int t = 0; t < 16; ++t) {
      if (t < 15) issueB(c, t + 1, (t & 1) ? SM_B0 : SM_B1);
      const int bufoff = (t & 1) ? SM_B1 : SM_B0;
      float bias = bb[t];
      f32x4 acc = { bias, bias, bias, bias };
      uint4 Bq[8];
#pragma unroll
      for (int ks = 0; ks < 8; ++ks)
        Bq[ks] = *(const uint4*)(smem + bufoff + (a * 8 + ks) * 1024 + lane * 16);
#pragma unroll
      for (int ks = 0; ks < 8; ++ks) {
        BF8 bf; bf.q = Bq[ks];
        acc = __builtin_amdgcn_mfma_f32_16x16x32_bf16(Af[ks].v, bf.v, acc, 0, 0, 0);
      }
      // fused scan step: partial += carry[r=t] * acc   (+ bias row at t=15)
      const float extra = (t == 15) ? 1.0f : 0.0f;
      const int   srcl  = (lane & 48) | t;
#pragma unroll
      for (int i = 0; i < 4; ++i) {
        float cv = __shfl(carry[i], srcl, 64) + extra;
        partial[i] += cv * acc[i];
      }
      __syncthreads();  // t+1 loads drained (overlapped with this tile's compute)
    }
    carry = partial;
  }

  // ---- epilogue: out[b][a*256+h] = carry[b][a][:] @ Uo[a][:][h] + bo[a][h]
  float uo[4][16], bov[4];
#pragma unroll
  for (int chk = 0; chk < 4; ++chk) {
    bov[chk] = bo[a * 256 + chk * 64 + lane];
#pragma unroll
    for (int r = 0; r < 16; ++r)
      uo[chk][r] = Uo[(size_t)a * 4096 + r * 256 + chk * 64 + lane];
  }
#pragma unroll
  for (int g = 0; g < 4; ++g)
#pragma unroll
    for (int i = 0; i < 4; ++i) {
      const int m = g * 4 + i;
      float cv[16];
#pragma unroll
      for (int r = 0; r < 16; ++r) cv[r] = __shfl(carry[i], (g << 4) | r, 64);
#pragma unroll
      for (int chk = 0; chk < 4; ++chk) {
        float v = bov[chk];
#pragma unroll
        for (int r = 0; r < 16; ++r) v += cv[r] * uo[chk][r];
        out[(size_t)(row0 + m) * 1024 + a * 256 + chk * 64 + lane] = v;
      }
    }
}

extern "C" void kernel_launch(void* const* d_in, const int* in_sizes, int n_in,
                              void* d_out, int out_size, void* d_ws, size_t ws_size,
                              hipStream_t stream) {
  const float* nh = (const float*)d_in[0];   // neighbour_h (16384, 8, 256)
  const float* ty = (const float*)d_in[1];   // type_embs   (16384, 64)
  const float* U  = (const float*)d_in[2];   // U           (8, 4, 256, 272)
  const float* bB = (const float*)d_in[3];   // b           (8, 4, 1, 272)
  const float* Ut = (const float*)d_in[4];   // U_type      (4, 64, 16)
  const float* bt = (const float*)d_in[5];   // b_type      (4, 1, 16)
  const float* Uo = (const float*)d_in[6];   // U_output    (4, 16, 256)
  const float* bo = (const float*)d_in[7];   // b_output    (4, 1, 256)
  float* out = (float*)d_out;

  unsigned int* Ubf32 = (unsigned int*)d_ws; // 4 MB frag-ordered bf16 U

  prep_U_kernel<<<4096, 256, 0, stream>>>(U, Ubf32);

  static int smem_set = 0;
  (void)hipFuncSetAttribute((const void*)tt_main,
                            hipFuncAttributeMaxDynamicSharedMemorySize, 98304);
  (void)smem_set;
  tt_main<<<256, 1024, 98304, stream>>>(nh, ty, (const char*)d_ws,
                                        bB, Ut, bt, Uo, bo, out);
}